// Round 1
// baseline (1232.741 us; speedup 1.0000x reference)
//
#include <hip/hip_runtime.h>
#include <hip/hip_bf16.h>

// Problem constants (must match reference)
#define BGR   256        // graphs
#define NPG1  512        // nodes per graph (input)
#define DEG   16
#define LB    5          // lookback features
#define DIM   64
#define OUTF  6
#define EDG   (BGR * NPG1 * DEG)   // 2,097,152
#define NN    (BGR * NPG1)         // 131,072
#define K1    410                  // ceil(0.8*512)
#define K2    328                  // ceil(0.8*410)
#define N1    (BGR * K1)           // 104,960
#define N2    (BGR * K2)           // 83,968

// ---------------------------------------------------------------------------
// Edge scatter for conv1: accumulate raw 5-dim x[src] into s1[dst], count deg.
__global__ void scatter1_kernel(const float* __restrict__ x,
                                const int* __restrict__ src,
                                const int* __restrict__ dst,
                                float* __restrict__ s1,
                                float* __restrict__ deg1) {
    int e = blockIdx.x * blockDim.x + threadIdx.x;
    if (e >= EDG) return;
    int s = src[e];
    int d = dst[e];
    #pragma unroll
    for (int j = 0; j < LB; ++j)
        atomicAdd(&s1[d * LB + j], x[s * LB + j]);
    atomicAdd(&deg1[d], 1.0f);
}

// ---------------------------------------------------------------------------
// conv1: h1[n,d] = relu( mean(n)@Wl + bl + x(n)@Wr ), plus pooling score.
// 4 nodes per 256-thread block, one wave (64 lanes) per node. NN % 4 == 0.
__global__ void conv1_kernel(const float* __restrict__ x,
                             const float* __restrict__ s1,
                             const float* __restrict__ deg1,
                             const float* __restrict__ Wl,
                             const float* __restrict__ bl,
                             const float* __restrict__ Wr,
                             const float* __restrict__ pw,
                             float* __restrict__ h1,
                             float* __restrict__ score1) {
    int wid  = threadIdx.x >> 6;
    int lane = threadIdx.x & 63;
    int n = blockIdx.x * 4 + wid;           // grid = NN/4, exact
    float invd = 1.0f / fmaxf(deg1[n], 1.0f);
    float m[LB], xv[LB];
    #pragma unroll
    for (int j = 0; j < LB; ++j) {
        m[j]  = s1[n * LB + j] * invd;
        xv[j] = x[n * LB + j];
    }
    float acc = bl[lane];
    #pragma unroll
    for (int j = 0; j < LB; ++j)
        acc += m[j] * Wl[j * DIM + lane] + xv[j] * Wr[j * DIM + lane];
    acc = fmaxf(acc, 0.0f);
    h1[(size_t)n * DIM + lane] = acc;
    // score = tanh(dot(h_row, pw) / ||pw||)
    float wv = pw[lane];
    float p = acc * wv;
    float q = wv * wv;
    #pragma unroll
    for (int o = 32; o > 0; o >>= 1) {
        p += __shfl_down(p, o);
        q += __shfl_down(q, o);
    }
    if (lane == 0) score1[n] = tanhf(p / sqrtf(q));
}

// ---------------------------------------------------------------------------
// TopK pooling: exact ranks per graph (descending, ties -> lower index),
// keep rank < K, write scaled rows in rank order; optionally write inv map.
template<int NPG, int KEEP, bool WRITE_INV>
__global__ void topk_pool_kernel(const float* __restrict__ score,
                                 const float* __restrict__ hin,
                                 float* __restrict__ hout,
                                 int* __restrict__ inv) {
    __shared__ float sc[NPG];
    int g = blockIdx.x;
    int t = threadIdx.x;                    // blockDim = 512
    if (t < NPG) sc[t] = score[g * NPG + t];
    __syncthreads();
    if (t < NPG) {
        float my = sc[t];
        int r = 0;
        for (int j = 0; j < NPG; ++j) {
            float v = sc[j];
            r += (v > my) || (v == my && j < t);
        }
        if (r < KEEP) {
            int oldid = g * NPG + t;
            int newid = g * KEEP + r;
            if (WRITE_INV) inv[oldid] = newid;
            const float4* s4 = (const float4*)(hin + (size_t)oldid * DIM);
            float4* d4 = (float4*)(hout + (size_t)newid * DIM);
            #pragma unroll
            for (int d = 0; d < DIM / 4; ++d) {
                float4 v = s4[d];
                v.x *= my; v.y *= my; v.z *= my; v.w *= my;
                d4[d] = v;
            }
        }
    }
}

// ---------------------------------------------------------------------------
// Readout: [max | mean] over K rows per graph -> xr[g][128]
template<int KEEP>
__global__ void readout_kernel(const float* __restrict__ hp,
                               float* __restrict__ xr) {
    int g = blockIdx.x;
    int d = threadIdx.x;                    // 64 threads
    const float* base = hp + (size_t)g * KEEP * DIM + d;
    float mx = -INFINITY, sm = 0.0f;
    for (int k = 0; k < KEEP; ++k) {
        float v = base[(size_t)k * DIM];
        mx = fmaxf(mx, v);
        sm += v;
    }
    xr[g * 2 * DIM + d]       = mx;
    xr[g * 2 * DIM + DIM + d] = sm * (1.0f / KEEP);
}

// ---------------------------------------------------------------------------
// Edge scatter for conv2: one wave per edge, lane = dim.
__global__ void scatter2_kernel(const int* __restrict__ src,
                                const int* __restrict__ dst,
                                const int* __restrict__ inv,
                                const float* __restrict__ h1p,
                                float* __restrict__ s2,
                                float* __restrict__ deg2) {
    long long idx = (long long)blockIdx.x * blockDim.x + threadIdx.x;
    int e    = (int)(idx >> 6);
    int lane = (int)(idx & 63);
    if (e >= EDG) return;
    int s = inv[src[e]];
    int d = inv[dst[e]];
    if (s < 0 || d < 0) return;
    atomicAdd(&s2[(size_t)d * DIM + lane], h1p[(size_t)s * DIM + lane]);
    if (lane == 0) atomicAdd(&deg2[d], 1.0f);
}

// ---------------------------------------------------------------------------
// conv2: h2[n,d] = relu( mean2(n)@Wl + bl + h1p(n)@Wr ), plus score2.
// 4 nodes per 256-thread block. N1 % 4 == 0.
__global__ void conv2_kernel(const float* __restrict__ s2,
                             const float* __restrict__ deg2,
                             const float* __restrict__ h1p,
                             const float* __restrict__ Wl,
                             const float* __restrict__ bl,
                             const float* __restrict__ Wr,
                             const float* __restrict__ pw,
                             float* __restrict__ h2,
                             float* __restrict__ score2) {
    __shared__ float mh[4][DIM];
    __shared__ float xh[4][DIM];
    int wid  = threadIdx.x >> 6;
    int lane = threadIdx.x & 63;
    int n = blockIdx.x * 4 + wid;           // grid = N1/4, exact
    float invd = 1.0f / fmaxf(deg2[n], 1.0f);
    mh[wid][lane] = s2[(size_t)n * DIM + lane] * invd;
    xh[wid][lane] = h1p[(size_t)n * DIM + lane];
    __syncthreads();
    float acc = bl[lane];
    #pragma unroll 8
    for (int j = 0; j < DIM; ++j)
        acc += mh[wid][j] * Wl[j * DIM + lane] + xh[wid][j] * Wr[j * DIM + lane];
    acc = fmaxf(acc, 0.0f);
    h2[(size_t)n * DIM + lane] = acc;
    float wv = pw[lane];
    float p = acc * wv;
    float q = wv * wv;
    #pragma unroll
    for (int o = 32; o > 0; o >>= 1) {
        p += __shfl_down(p, o);
        q += __shfl_down(q, o);
    }
    if (lane == 0) score2[n] = tanhf(p / sqrtf(q));
}

// ---------------------------------------------------------------------------
// Final: z = x1 + x2; y = relu(z@W1 + b1); out = y@W2 + b2.
__global__ void final_kernel(const float* __restrict__ x1,
                             const float* __restrict__ x2,
                             const float* __restrict__ W1,
                             const float* __restrict__ b1,
                             const float* __restrict__ W2,
                             const float* __restrict__ b2,
                             float* __restrict__ out) {
    __shared__ float z[2 * DIM];
    __shared__ float y[DIM];
    int g = blockIdx.x;
    int t = threadIdx.x;                    // 128 threads
    z[t] = x1[g * 2 * DIM + t] + x2[g * 2 * DIM + t];
    __syncthreads();
    if (t < DIM) {
        float a = b1[t];
        #pragma unroll 8
        for (int j = 0; j < 2 * DIM; ++j)
            a += z[j] * W1[j * DIM + t];
        y[t] = fmaxf(a, 0.0f);
    }
    __syncthreads();
    if (t < OUTF) {
        float a = b2[t];
        #pragma unroll 8
        for (int j = 0; j < DIM; ++j)
            a += y[j] * W2[j * OUTF + t];
        out[g * OUTF + t] = a;
    }
}

// ---------------------------------------------------------------------------
extern "C" void kernel_launch(void* const* d_in, const int* in_sizes, int n_in,
                              void* d_out, int out_size, void* d_ws, size_t ws_size,
                              hipStream_t stream) {
    (void)in_sizes; (void)n_in; (void)out_size; (void)ws_size;
    const float* x       = (const float*)d_in[0];
    const int*   eidx    = (const int*)d_in[1];
    const float* c1_Wl   = (const float*)d_in[2];
    const float* c1_bl   = (const float*)d_in[3];
    const float* c1_Wr   = (const float*)d_in[4];
    const float* pool1_w = (const float*)d_in[5];
    const float* c2_Wl   = (const float*)d_in[6];
    const float* c2_bl   = (const float*)d_in[7];
    const float* c2_Wr   = (const float*)d_in[8];
    const float* pool2_w = (const float*)d_in[9];
    const float* lin1_W  = (const float*)d_in[10];
    const float* lin1_b  = (const float*)d_in[11];
    const float* lin2_W  = (const float*)d_in[12];
    const float* lin2_b  = (const float*)d_in[13];
    float* out = (float*)d_out;

    const int* src = eidx;
    const int* dst = eidx + EDG;

    // Workspace layout (bytes, 256-aligned)
    char* w = (char*)d_ws;
    size_t off = 0;
    auto alloc = [&](size_t bytes) {
        void* p = w + off;
        off = (off + bytes + 255) & ~(size_t)255;
        return p;
    };
    float* s1     = (float*)alloc((size_t)NN * LB * 4);
    float* deg1   = (float*)alloc((size_t)NN * 4);
    float* score1 = (float*)alloc((size_t)NN * 4);
    int*   inv    = (int*)  alloc((size_t)NN * 4);
    float* deg2   = (float*)alloc((size_t)N1 * 4);
    float* score2 = (float*)alloc((size_t)N1 * 4);
    float* x1buf  = (float*)alloc((size_t)BGR * 2 * DIM * 4);
    float* x2buf  = (float*)alloc((size_t)BGR * 2 * DIM * 4);
    float* h1     = (float*)alloc((size_t)NN * DIM * 4);   // reused as s2 later
    float* h1p    = (float*)alloc((size_t)N1 * DIM * 4);   // reused as h2p later
    float* h2     = (float*)alloc((size_t)N1 * DIM * 4);
    float* s2  = h1;    // NN*64 >= N1*64, h1 dead after pool1
    float* h2p = h1p;   // h1p dead after conv2

    // conv1 aggregation
    hipMemsetAsync(s1,   0,    (size_t)NN * LB * 4, stream);
    hipMemsetAsync(deg1, 0,    (size_t)NN * 4, stream);
    hipMemsetAsync(inv,  0xFF, (size_t)NN * 4, stream);   // -1
    scatter1_kernel<<<EDG / 256, 256, 0, stream>>>(x, src, dst, s1, deg1);
    conv1_kernel<<<NN / 4, 256, 0, stream>>>(x, s1, deg1, c1_Wl, c1_bl, c1_Wr,
                                             pool1_w, h1, score1);
    topk_pool_kernel<NPG1, K1, true><<<BGR, 512, 0, stream>>>(score1, h1, h1p, inv);
    readout_kernel<K1><<<BGR, 64, 0, stream>>>(h1p, x1buf);

    // conv2 aggregation (s2 overlays h1 — zero after pool1 consumed h1)
    hipMemsetAsync(s2,   0, (size_t)N1 * DIM * 4, stream);
    hipMemsetAsync(deg2, 0, (size_t)N1 * 4, stream);
    {
        long long threads = (long long)EDG * 64;
        int blocks = (int)(threads / 256);
        scatter2_kernel<<<blocks, 256, 0, stream>>>(src, dst, inv, h1p, s2, deg2);
    }
    conv2_kernel<<<N1 / 4, 256, 0, stream>>>(s2, deg2, h1p, c2_Wl, c2_bl, c2_Wr,
                                             pool2_w, h2, score2);
    topk_pool_kernel<K1, K2, false><<<BGR, 512, 0, stream>>>(score2, h2, h2p, nullptr);
    readout_kernel<K2><<<BGR, 64, 0, stream>>>(h2p, x2buf);

    final_kernel<<<BGR, 128, 0, stream>>>(x1buf, x2buf, lin1_W, lin1_b,
                                          lin2_W, lin2_b, out);
}

// Round 2
// 647.751 us; speedup vs baseline: 1.9031x; 1.9031x over previous
//
#include <hip/hip_runtime.h>
#include <hip/hip_bf16.h>

// Problem constants
#define BGR   256                 // graphs
#define NPG1  512                 // nodes per graph (input)
#define DEG   16
#define EPG   (NPG1 * DEG)        // 8192 edges per graph
#define LB    5                   // lookback features
#define DIM   64
#define OUTF  6
#define NN    (BGR * NPG1)        // 131,072
#define K1    410                 // ceil(0.8*512)
#define K2    328                 // ceil(0.8*410)
#define N1    (BGR * K1)          // 104,960

// ---------------------------------------------------------------------------
// Stage 1 (one block per graph, 512 threads = 8 waves):
// LDS edge aggregation -> conv1 -> score -> exact-rank topk -> write scaled
// h1p rows + local-rank inv map + readout x1.
__global__ __launch_bounds__(512)
void stage1_kernel(const float* __restrict__ x,
                   const int* __restrict__ eidx,
                   const float* __restrict__ Wl,
                   const float* __restrict__ bl,
                   const float* __restrict__ Wr,
                   const float* __restrict__ pw,
                   float* __restrict__ h1p,
                   int* __restrict__ invr,
                   float* __restrict__ x1buf) {
    __shared__ float xl[NPG1 * LB];      // 10 KB raw features
    __shared__ float sums[NPG1 * LB];    // 10 KB aggregation
    __shared__ float deg[NPG1];
    __shared__ float sc[NPG1];
    __shared__ int   rnk[NPG1];
    __shared__ float redmx[8 * DIM];
    __shared__ float redsm[8 * DIM];

    const int g = blockIdx.x, t = threadIdx.x;
    const int wid = t >> 6, lane = t & 63;
    const int* __restrict__ src = eidx;
    const int* __restrict__ dst = eidx + (BGR * EPG);

    for (int i = t; i < NPG1 * LB; i += 512) {
        xl[i]   = x[(size_t)g * (NPG1 * LB) + i];
        sums[i] = 0.f;
    }
    deg[t] = 0.f;                        // blockDim == NPG1 == 512
    __syncthreads();

    // Edge aggregation into LDS (random-bank LDS atomics, cheap)
    const int ebase = g * EPG;
    #pragma unroll
    for (int k = 0; k < EPG / 512; ++k) {
        int e = ebase + k * 512 + t;
        int s = src[e] & (NPG1 - 1);     // local ids (offsets are g*512)
        int d = dst[e] & (NPG1 - 1);
        #pragma unroll
        for (int j = 0; j < LB; ++j)
            atomicAdd(&sums[d * LB + j], xl[s * LB + j]);
        atomicAdd(&deg[d], 1.f);
    }
    __syncthreads();

    // Per-lane weight preload (5x64 each)
    float wlv[LB], wrv[LB];
    #pragma unroll
    for (int j = 0; j < LB; ++j) { wlv[j] = Wl[j * DIM + lane]; wrv[j] = Wr[j * DIM + lane]; }
    const float blv = bl[lane], pwv = pw[lane];
    float q = pwv * pwv;
    #pragma unroll
    for (int o = 32; o; o >>= 1) q += __shfl_xor(q, o);
    const float inv_nrm = 1.f / sqrtf(q);

    // Pass 1: scores only (wave per node, lane = dim)
    for (int n = wid; n < NPG1; n += 8) {
        float invd = 1.f / fmaxf(deg[n], 1.f);
        float acc = blv;
        #pragma unroll
        for (int j = 0; j < LB; ++j)
            acc += sums[n * LB + j] * invd * wlv[j] + xl[n * LB + j] * wrv[j];
        acc = fmaxf(acc, 0.f);
        float p = acc * pwv;
        #pragma unroll
        for (int o = 32; o; o >>= 1) p += __shfl_xor(p, o);
        if (lane == 0) sc[n] = tanhf(p * inv_nrm);
    }
    __syncthreads();

    // Exact ranks (descending, ties -> lower index); write inv map
    {
        float my = sc[t];
        int r = 0;
        for (int j = 0; j < NPG1; ++j) {
            float v = sc[j];
            r += (v > my) || (v == my && j < t);
        }
        rnk[t] = r;
        invr[g * NPG1 + t] = (r < K1) ? r : -1;
    }
    __syncthreads();

    // Pass 2: recompute kept rows (10 FMA/node), write scaled, readout accum
    float mx = -INFINITY, sm = 0.f;
    for (int n = wid; n < NPG1; n += 8) {
        int r = rnk[n];
        if (r >= K1) continue;
        float invd = 1.f / fmaxf(deg[n], 1.f);
        float acc = blv;
        #pragma unroll
        for (int j = 0; j < LB; ++j)
            acc += sums[n * LB + j] * invd * wlv[j] + xl[n * LB + j] * wrv[j];
        acc = fmaxf(acc, 0.f);
        float v = acc * sc[n];
        h1p[((size_t)g * K1 + r) * DIM + lane] = v;
        mx = fmaxf(mx, v);
        sm += v;
    }
    redmx[wid * DIM + lane] = mx;
    redsm[wid * DIM + lane] = sm;
    __syncthreads();
    if (wid == 0) {
        float m2 = redmx[lane], s2 = redsm[lane];
        #pragma unroll
        for (int w = 1; w < 8; ++w) {
            m2 = fmaxf(m2, redmx[w * DIM + lane]);
            s2 += redsm[w * DIM + lane];
        }
        x1buf[g * 2 * DIM + lane]       = m2;
        x1buf[g * 2 * DIM + DIM + lane] = s2 * (1.0f / (float)K1);
    }
}

// ---------------------------------------------------------------------------
// Stage 2 (one block per graph, 512 threads = 8 waves):
// edge filter+compact -> LDS aggregation -> conv2 (W in VGPRs) -> topk2 ->
// readout2 -> fused final MLP -> out.
__global__ __launch_bounds__(512, 2)
void stage2_kernel(const int* __restrict__ eidx,
                   const int* __restrict__ invr,
                   const float* __restrict__ h1p,
                   const float* __restrict__ Wl,
                   const float* __restrict__ bl,
                   const float* __restrict__ Wr,
                   const float* __restrict__ pw,
                   const float* __restrict__ x1buf,
                   const float* __restrict__ W1,
                   const float* __restrict__ b1,
                   const float* __restrict__ W2,
                   const float* __restrict__ b2,
                   float* __restrict__ out) {
    __shared__ __align__(16) float sums2[(K1 + 1) * DIM];   // 105,216 B (+dummy row)
    __shared__ __align__(16) int   elist[EPG];              // 32,768 B
    __shared__ float deg2[K1 + 1];
    __shared__ float sc2[K1];
    __shared__ int   rnk2[K1];
    __shared__ float redmx[8 * DIM];
    __shared__ float redsm[8 * DIM];
    __shared__ float zy[2 * DIM + DIM];                     // z (128) | y (64)
    __shared__ int   cnt;

    const int g = blockIdx.x, t = threadIdx.x;
    const int wid = t >> 6, lane = t & 63;
    const int* __restrict__ src = eidx;
    const int* __restrict__ dst = eidx + (BGR * EPG);
    const float* __restrict__ hg = h1p + (size_t)g * K1 * DIM;

    for (int i = t; i < (K1 + 1) * DIM; i += 512) sums2[i] = 0.f;
    if (t < K1 + 1) deg2[t] = 0.f;
    if (t == 0) cnt = 0;
    __syncthreads();

    // Filter edges via inv map; ballot-compact (rs,rd) pairs into LDS
    const int ebase = g * EPG;
    #pragma unroll
    for (int k = 0; k < EPG / 512; ++k) {
        int e = ebase + k * 512 + t;
        int rs = invr[src[e]];
        int rd = invr[dst[e]];
        bool valid = (rs >= 0) && (rd >= 0);
        unsigned long long m = __ballot(valid);
        int base = 0;
        if (lane == 0 && m) base = atomicAdd(&cnt, __popcll(m));
        base = __shfl(base, 0);
        if (valid) {
            int pos = base + __popcll(m & ((1ull << lane) - 1ull));
            elist[pos] = (rs << 16) | rd;
            atomicAdd(&deg2[rd], 1.f);
        }
    }
    __syncthreads();
    const int nv  = cnt;
    const int nvp = (nv + 31) & ~31;
    for (int i = nv + t; i < nvp; i += 512) elist[i] = K1;  // dummy: rs=0, rd=K1
    __syncthreads();

    // Aggregate h1p[src] rows into LDS (4 edges per wave-iteration for MLP)
    for (int i = wid * 4; i < nvp; i += 32) {
        int4 pk = *(const int4*)&elist[i];                  // broadcast b128
        float v0 = hg[(pk.x >> 16) * DIM + lane];
        float v1 = hg[(pk.y >> 16) * DIM + lane];
        float v2 = hg[(pk.z >> 16) * DIM + lane];
        float v3 = hg[(pk.w >> 16) * DIM + lane];
        atomicAdd(&sums2[(pk.x & 0xffff) * DIM + lane], v0);
        atomicAdd(&sums2[(pk.y & 0xffff) * DIM + lane], v1);
        atomicAdd(&sums2[(pk.z & 0xffff) * DIM + lane], v2);
        atomicAdd(&sums2[(pk.w & 0xffff) * DIM + lane], v3);
    }
    __syncthreads();

    // Pre-scale rows by 1/max(deg,1)  (rows 0..K1-1 only)
    for (int i = t; i < K1 * DIM; i += 512) {
        int n = i >> 6;
        sums2[i] *= 1.f / fmaxf(deg2[n], 1.f);
    }

    // Preload W columns into registers: lane d holds Wl[:,d], Wr[:,d]
    float wl[DIM], wr[DIM];
    #pragma unroll
    for (int j = 0; j < DIM; ++j) {
        wl[j] = Wl[j * DIM + lane];
        wr[j] = Wr[j * DIM + lane];
    }
    const float blv = bl[lane], pwv = pw[lane];
    float q = pwv * pwv;
    #pragma unroll
    for (int o = 32; o; o >>= 1) q += __shfl_xor(q, o);
    const float inv_nrm = 1.f / sqrtf(q);
    __syncthreads();

    // conv2: wave per node; mean via LDS b128 broadcast, x via global b128
    // broadcast (L1/L2-hot), weights from registers. h2 overwrites sums2 row.
    for (int n = wid; n < K1; n += 8) {
        const float4* mrow = (const float4*)&sums2[n * DIM];
        const float4* xrow = (const float4*)&hg[(size_t)n * DIM];
        float acc = blv;
        #pragma unroll
        for (int j4 = 0; j4 < DIM / 4; ++j4) {
            float4 m  = mrow[j4];
            float4 xq = xrow[j4];
            acc += m.x  * wl[4 * j4]     + m.y  * wl[4 * j4 + 1]
                 + m.z  * wl[4 * j4 + 2] + m.w  * wl[4 * j4 + 3]
                 + xq.x * wr[4 * j4]     + xq.y * wr[4 * j4 + 1]
                 + xq.z * wr[4 * j4 + 2] + xq.w * wr[4 * j4 + 3];
        }
        acc = fmaxf(acc, 0.f);
        sums2[n * DIM + lane] = acc;     // h2 row (read-before-write, same wave)
        float p = acc * pwv;
        #pragma unroll
        for (int o = 32; o; o >>= 1) p += __shfl_xor(p, o);
        if (lane == 0) sc2[n] = tanhf(p * inv_nrm);
    }
    __syncthreads();

    // Ranks over K1 scores
    if (t < K1) {
        float my = sc2[t];
        int r = 0;
        for (int j = 0; j < K1; ++j) {
            float v = sc2[j];
            r += (v > my) || (v == my && j < t);
        }
        rnk2[t] = r;
    }
    __syncthreads();

    // Readout over kept (rank < K2) scaled rows
    float mx = -INFINITY, sm = 0.f;
    for (int n = wid; n < K1; n += 8) {
        if (rnk2[n] < K2) {
            float v = sums2[n * DIM + lane] * sc2[n];
            mx = fmaxf(mx, v);
            sm += v;
        }
    }
    redmx[wid * DIM + lane] = mx;
    redsm[wid * DIM + lane] = sm;
    __syncthreads();
    if (wid == 0) {
        float m2 = redmx[lane], s2 = redsm[lane];
        #pragma unroll
        for (int w = 1; w < 8; ++w) {
            m2 = fmaxf(m2, redmx[w * DIM + lane]);
            s2 += redsm[w * DIM + lane];
        }
        zy[lane]       = x1buf[g * 2 * DIM + lane]       + m2;
        zy[DIM + lane] = x1buf[g * 2 * DIM + DIM + lane] + s2 * (1.0f / (float)K2);
    }
    __syncthreads();

    // Final MLP: y = relu(z@W1 + b1); out = y@W2 + b2
    if (t < DIM) {
        float a = b1[t];
        #pragma unroll 8
        for (int j = 0; j < 2 * DIM; ++j) a += zy[j] * W1[j * DIM + t];
        zy[2 * DIM + t] = fmaxf(a, 0.f);
    }
    __syncthreads();
    if (t < OUTF) {
        float a = b2[t];
        #pragma unroll
        for (int j = 0; j < DIM; ++j) a += zy[2 * DIM + j] * W2[j * OUTF + t];
        out[g * OUTF + t] = a;
    }
}

// ---------------------------------------------------------------------------
extern "C" void kernel_launch(void* const* d_in, const int* in_sizes, int n_in,
                              void* d_out, int out_size, void* d_ws, size_t ws_size,
                              hipStream_t stream) {
    (void)in_sizes; (void)n_in; (void)out_size; (void)ws_size;
    const float* x       = (const float*)d_in[0];
    const int*   eidx    = (const int*)d_in[1];
    const float* c1_Wl   = (const float*)d_in[2];
    const float* c1_bl   = (const float*)d_in[3];
    const float* c1_Wr   = (const float*)d_in[4];
    const float* pool1_w = (const float*)d_in[5];
    const float* c2_Wl   = (const float*)d_in[6];
    const float* c2_bl   = (const float*)d_in[7];
    const float* c2_Wr   = (const float*)d_in[8];
    const float* pool2_w = (const float*)d_in[9];
    const float* lin1_W  = (const float*)d_in[10];
    const float* lin1_b  = (const float*)d_in[11];
    const float* lin2_W  = (const float*)d_in[12];
    const float* lin2_b  = (const float*)d_in[13];
    float* out = (float*)d_out;

    // Workspace layout (256-aligned)
    char* w = (char*)d_ws;
    size_t off = 0;
    auto alloc = [&](size_t bytes) {
        void* p = w + off;
        off = (off + bytes + 255) & ~(size_t)255;
        return p;
    };
    float* h1p   = (float*)alloc((size_t)N1 * DIM * 4);      // 26.9 MB
    int*   invr  = (int*)  alloc((size_t)NN * 4);            // 512 KB
    float* x1buf = (float*)alloc((size_t)BGR * 2 * DIM * 4); // 128 KB

    stage1_kernel<<<BGR, 512, 0, stream>>>(x, eidx, c1_Wl, c1_bl, c1_Wr,
                                           pool1_w, h1p, invr, x1buf);
    stage2_kernel<<<BGR, 512, 0, stream>>>(eidx, invr, h1p, c2_Wl, c2_bl, c2_Wr,
                                           pool2_w, x1buf, lin1_W, lin1_b,
                                           lin2_W, lin2_b, out);
}

// Round 3
// 629.579 us; speedup vs baseline: 1.9580x; 1.0289x over previous
//
#include <hip/hip_runtime.h>
#include <hip/hip_bf16.h>

// Problem constants
#define BGR   256                 // graphs
#define NPG1  512                 // nodes per graph (input)
#define DEG   16
#define EPG   (NPG1 * DEG)        // 8192 edges per graph
#define LB    5                   // lookback features
#define DIM   64
#define OUTF  6
#define NN    (BGR * NPG1)        // 131,072
#define K1    410                 // ceil(0.8*512)
#define K2    328                 // ceil(0.8*410)
#define N1    (BGR * K1)          // 104,960

// ---------------------------------------------------------------------------
// Stage 1 (one block per graph, 512 threads = 8 waves):
// LDS edge aggregation (native ds_add_f32 via unsafeAtomicAdd) -> conv1 ->
// score -> exact-rank topk -> scaled h1p rows + inv map + readout x1.
__global__ __launch_bounds__(512)
void stage1_kernel(const float* __restrict__ x,
                   const int* __restrict__ eidx,
                   const float* __restrict__ Wl,
                   const float* __restrict__ bl,
                   const float* __restrict__ Wr,
                   const float* __restrict__ pw,
                   float* __restrict__ h1p,
                   int* __restrict__ invr,
                   float* __restrict__ x1buf) {
    __shared__ float xl[NPG1 * LB];      // 10 KB raw features
    __shared__ float sums[NPG1 * LB];    // 10 KB aggregation
    __shared__ int   degi[NPG1];
    __shared__ float sc[NPG1];
    __shared__ int   rnk[NPG1];
    __shared__ float redmx[8 * DIM];
    __shared__ float redsm[8 * DIM];

    const int g = blockIdx.x, t = threadIdx.x;
    const int wid = t >> 6, lane = t & 63;
    const int* __restrict__ src = eidx;
    const int* __restrict__ dst = eidx + (BGR * EPG);

    for (int i = t; i < NPG1 * LB; i += 512) {
        xl[i]   = x[(size_t)g * (NPG1 * LB) + i];
        sums[i] = 0.f;
    }
    degi[t] = 0;                         // blockDim == NPG1 == 512
    __syncthreads();

    // Edge aggregation into LDS — native float LDS atomics
    const int ebase = g * EPG;
    #pragma unroll
    for (int k = 0; k < EPG / 512; ++k) {
        int e = ebase + k * 512 + t;
        int s = src[e] & (NPG1 - 1);     // local ids (offsets are g*512)
        int d = dst[e] & (NPG1 - 1);
        #pragma unroll
        for (int j = 0; j < LB; ++j)
            unsafeAtomicAdd(&sums[d * LB + j], xl[s * LB + j]);
        atomicAdd(&degi[d], 1);
    }
    __syncthreads();

    // Per-lane weight preload (5x64 each)
    float wlv[LB], wrv[LB];
    #pragma unroll
    for (int j = 0; j < LB; ++j) { wlv[j] = Wl[j * DIM + lane]; wrv[j] = Wr[j * DIM + lane]; }
    const float blv = bl[lane], pwv = pw[lane];
    float q = pwv * pwv;
    #pragma unroll
    for (int o = 32; o; o >>= 1) q += __shfl_xor(q, o);
    const float inv_nrm = 1.f / sqrtf(q);

    // Pass 1: scores (wave per node, lane = dim)
    for (int n = wid; n < NPG1; n += 8) {
        float invd = 1.f / fmaxf((float)degi[n], 1.f);
        float al = 0.f, ar = 0.f;
        #pragma unroll
        for (int j = 0; j < LB; ++j) {
            al += sums[n * LB + j] * wlv[j];
            ar += xl[n * LB + j] * wrv[j];
        }
        float acc = fmaxf(blv + al * invd + ar, 0.f);
        float p = acc * pwv;
        #pragma unroll
        for (int o = 32; o; o >>= 1) p += __shfl_xor(p, o);
        if (lane == 0) sc[n] = tanhf(p * inv_nrm);
    }
    __syncthreads();

    // Exact ranks (descending, ties -> lower index); write inv map
    {
        float my = sc[t];
        int r = 0;
        for (int j = 0; j < NPG1; ++j) {
            float v = sc[j];
            r += (v > my) || (v == my && j < t);
        }
        rnk[t] = r;
        invr[g * NPG1 + t] = (r < K1) ? r : -1;
    }
    __syncthreads();

    // Pass 2: recompute kept rows, write scaled, readout accum
    float mx = -INFINITY, sm = 0.f;
    for (int n = wid; n < NPG1; n += 8) {
        int r = rnk[n];
        if (r >= K1) continue;
        float invd = 1.f / fmaxf((float)degi[n], 1.f);
        float al = 0.f, ar = 0.f;
        #pragma unroll
        for (int j = 0; j < LB; ++j) {
            al += sums[n * LB + j] * wlv[j];
            ar += xl[n * LB + j] * wrv[j];
        }
        float acc = fmaxf(blv + al * invd + ar, 0.f);
        float v = acc * sc[n];
        h1p[((size_t)g * K1 + r) * DIM + lane] = v;
        mx = fmaxf(mx, v);
        sm += v;
    }
    redmx[wid * DIM + lane] = mx;
    redsm[wid * DIM + lane] = sm;
    __syncthreads();
    if (wid == 0) {
        float m2 = redmx[lane], s2 = redsm[lane];
        #pragma unroll
        for (int w = 1; w < 8; ++w) {
            m2 = fmaxf(m2, redmx[w * DIM + lane]);
            s2 += redsm[w * DIM + lane];
        }
        x1buf[g * 2 * DIM + lane]       = m2;
        x1buf[g * 2 * DIM + DIM + lane] = s2 * (1.0f / (float)K1);
    }
}

// ---------------------------------------------------------------------------
// Stage 2 (one block per graph, 512 threads = 8 waves):
// edge filter+compact -> pipelined LDS aggregation (native atomics) ->
// conv2 (W in VGPRs) -> topk2 -> readout2 -> fused final MLP -> out.
__global__ __launch_bounds__(512)
void stage2_kernel(const int* __restrict__ eidx,
                   const int* __restrict__ invr,
                   const float* __restrict__ h1p,
                   const float* __restrict__ Wl,
                   const float* __restrict__ bl,
                   const float* __restrict__ Wr,
                   const float* __restrict__ pw,
                   const float* __restrict__ x1buf,
                   const float* __restrict__ W1,
                   const float* __restrict__ b1,
                   const float* __restrict__ W2,
                   const float* __restrict__ b2,
                   float* __restrict__ out) {
    __shared__ __align__(16) float sums2[(K1 + 1) * DIM];   // 105,216 B (+dummy row)
    __shared__ __align__(16) int   elist[EPG];              // 32,768 B
    __shared__ int   deg2i[K1 + 1];
    __shared__ float sc2[K1];
    __shared__ int   rnk2[K1];
    __shared__ float redmx[8 * DIM];
    __shared__ float redsm[8 * DIM];
    __shared__ float zy[2 * DIM + DIM];                     // z (128) | y (64)
    __shared__ int   cnt;

    const int g = blockIdx.x, t = threadIdx.x;
    const int wid = t >> 6, lane = t & 63;
    const int* __restrict__ src = eidx;
    const int* __restrict__ dst = eidx + (BGR * EPG);
    const float* __restrict__ hg = h1p + (size_t)g * K1 * DIM;

    for (int i = t; i < (K1 + 1) * DIM; i += 512) sums2[i] = 0.f;
    if (t < K1 + 1) deg2i[t] = 0;
    if (t == 0) cnt = 0;
    __syncthreads();

    // Filter edges via inv map; ballot-compact (rs,rd) pairs into LDS
    const int ebase = g * EPG;
    #pragma unroll
    for (int k = 0; k < EPG / 512; ++k) {
        int e = ebase + k * 512 + t;
        int rs = invr[src[e]];
        int rd = invr[dst[e]];
        bool valid = (rs >= 0) && (rd >= 0);
        unsigned long long m = __ballot(valid);
        int base = 0;
        if (lane == 0 && m) base = atomicAdd(&cnt, __popcll(m));
        base = __shfl(base, 0);
        if (valid) {
            int pos = base + __popcll(m & ((1ull << lane) - 1ull));
            elist[pos] = (rs << 16) | rd;
            atomicAdd(&deg2i[rd], 1);
        }
    }
    __syncthreads();
    const int nv  = cnt;
    const int nvp = (nv + 63) & ~63;
    for (int i = nv + t; i < nvp; i += 512) elist[i] = K1;  // dummy: rs=0, rd=K1
    __syncthreads();

    // Aggregate h1p[src] rows into LDS — 8 edges per wave-iteration so 8
    // independent 256B row loads are in flight before the atomics.
    for (int i = wid * 8; i < nvp; i += 64) {
        int4 a = *(const int4*)&elist[i];
        int4 b = *(const int4*)&elist[i + 4];
        float v0 = hg[(a.x >> 16) * DIM + lane];
        float v1 = hg[(a.y >> 16) * DIM + lane];
        float v2 = hg[(a.z >> 16) * DIM + lane];
        float v3 = hg[(a.w >> 16) * DIM + lane];
        float v4 = hg[(b.x >> 16) * DIM + lane];
        float v5 = hg[(b.y >> 16) * DIM + lane];
        float v6 = hg[(b.z >> 16) * DIM + lane];
        float v7 = hg[(b.w >> 16) * DIM + lane];
        unsafeAtomicAdd(&sums2[(a.x & 0xffff) * DIM + lane], v0);
        unsafeAtomicAdd(&sums2[(a.y & 0xffff) * DIM + lane], v1);
        unsafeAtomicAdd(&sums2[(a.z & 0xffff) * DIM + lane], v2);
        unsafeAtomicAdd(&sums2[(a.w & 0xffff) * DIM + lane], v3);
        unsafeAtomicAdd(&sums2[(b.x & 0xffff) * DIM + lane], v4);
        unsafeAtomicAdd(&sums2[(b.y & 0xffff) * DIM + lane], v5);
        unsafeAtomicAdd(&sums2[(b.z & 0xffff) * DIM + lane], v6);
        unsafeAtomicAdd(&sums2[(b.w & 0xffff) * DIM + lane], v7);
    }

    // Preload W columns into registers: lane d holds Wl[:,d], Wr[:,d]
    float wl[DIM], wr[DIM];
    #pragma unroll
    for (int j = 0; j < DIM; ++j) {
        wl[j] = Wl[j * DIM + lane];
        wr[j] = Wr[j * DIM + lane];
    }
    const float blv = bl[lane], pwv = pw[lane];
    float q = pwv * pwv;
    #pragma unroll
    for (int o = 32; o; o >>= 1) q += __shfl_xor(q, o);
    const float inv_nrm = 1.f / sqrtf(q);
    __syncthreads();

    // conv2: wave per node; mean scale folded in algebraically.
    for (int n = wid; n < K1; n += 8) {
        float invd = 1.f / fmaxf((float)deg2i[n], 1.f);
        const float4* mrow = (const float4*)&sums2[n * DIM];
        const float4* xrow = (const float4*)&hg[(size_t)n * DIM];
        float al = 0.f, ar = 0.f;
        #pragma unroll
        for (int j4 = 0; j4 < DIM / 4; ++j4) {
            float4 m  = mrow[j4];
            float4 xq = xrow[j4];
            al += m.x  * wl[4 * j4]     + m.y  * wl[4 * j4 + 1]
                + m.z  * wl[4 * j4 + 2] + m.w  * wl[4 * j4 + 3];
            ar += xq.x * wr[4 * j4]     + xq.y * wr[4 * j4 + 1]
                + xq.z * wr[4 * j4 + 2] + xq.w * wr[4 * j4 + 3];
        }
        float acc = fmaxf(blv + al * invd + ar, 0.f);
        sums2[n * DIM + lane] = acc;     // h2 row (same wave re-reads only)
        float p = acc * pwv;
        #pragma unroll
        for (int o = 32; o; o >>= 1) p += __shfl_xor(p, o);
        if (lane == 0) sc2[n] = tanhf(p * inv_nrm);
    }
    __syncthreads();

    // Ranks over K1 scores
    if (t < K1) {
        float my = sc2[t];
        int r = 0;
        for (int j = 0; j < K1; ++j) {
            float v = sc2[j];
            r += (v > my) || (v == my && j < t);
        }
        rnk2[t] = r;
    }
    __syncthreads();

    // Readout over kept (rank < K2) scaled rows
    float mx = -INFINITY, sm = 0.f;
    for (int n = wid; n < K1; n += 8) {
        if (rnk2[n] < K2) {
            float v = sums2[n * DIM + lane] * sc2[n];
            mx = fmaxf(mx, v);
            sm += v;
        }
    }
    redmx[wid * DIM + lane] = mx;
    redsm[wid * DIM + lane] = sm;
    __syncthreads();
    if (wid == 0) {
        float m2 = redmx[lane], s2 = redsm[lane];
        #pragma unroll
        for (int w = 1; w < 8; ++w) {
            m2 = fmaxf(m2, redmx[w * DIM + lane]);
            s2 += redsm[w * DIM + lane];
        }
        zy[lane]       = x1buf[g * 2 * DIM + lane]       + m2;
        zy[DIM + lane] = x1buf[g * 2 * DIM + DIM + lane] + s2 * (1.0f / (float)K2);
    }
    __syncthreads();

    // Final MLP: y = relu(z@W1 + b1); out = y@W2 + b2
    if (t < DIM) {
        float a = b1[t];
        #pragma unroll 8
        for (int j = 0; j < 2 * DIM; ++j) a += zy[j] * W1[j * DIM + t];
        zy[2 * DIM + t] = fmaxf(a, 0.f);
    }
    __syncthreads();
    if (t < OUTF) {
        float a = b2[t];
        #pragma unroll
        for (int j = 0; j < DIM; ++j) a += zy[2 * DIM + j] * W2[j * OUTF + t];
        out[g * OUTF + t] = a;
    }
}

// ---------------------------------------------------------------------------
extern "C" void kernel_launch(void* const* d_in, const int* in_sizes, int n_in,
                              void* d_out, int out_size, void* d_ws, size_t ws_size,
                              hipStream_t stream) {
    (void)in_sizes; (void)n_in; (void)out_size; (void)ws_size;
    const float* x       = (const float*)d_in[0];
    const int*   eidx    = (const int*)d_in[1];
    const float* c1_Wl   = (const float*)d_in[2];
    const float* c1_bl   = (const float*)d_in[3];
    const float* c1_Wr   = (const float*)d_in[4];
    const float* pool1_w = (const float*)d_in[5];
    const float* c2_Wl   = (const float*)d_in[6];
    const float* c2_bl   = (const float*)d_in[7];
    const float* c2_Wr   = (const float*)d_in[8];
    const float* pool2_w = (const float*)d_in[9];
    const float* lin1_W  = (const float*)d_in[10];
    const float* lin1_b  = (const float*)d_in[11];
    const float* lin2_W  = (const float*)d_in[12];
    const float* lin2_b  = (const float*)d_in[13];
    float* out = (float*)d_out;

    // Workspace layout (256-aligned)
    char* w = (char*)d_ws;
    size_t off = 0;
    auto alloc = [&](size_t bytes) {
        void* p = w + off;
        off = (off + bytes + 255) & ~(size_t)255;
        return p;
    };
    float* h1p   = (float*)alloc((size_t)N1 * DIM * 4);      // 26.9 MB
    int*   invr  = (int*)  alloc((size_t)NN * 4);            // 512 KB
    float* x1buf = (float*)alloc((size_t)BGR * 2 * DIM * 4); // 128 KB

    stage1_kernel<<<BGR, 512, 0, stream>>>(x, eidx, c1_Wl, c1_bl, c1_Wr,
                                           pool1_w, h1p, invr, x1buf);
    stage2_kernel<<<BGR, 512, 0, stream>>>(eidx, invr, h1p, c2_Wl, c2_bl, c2_Wr,
                                           pool2_w, x1buf, lin1_W, lin1_b,
                                           lin2_W, lin2_b, out);
}